// Round 7
// baseline (87.085 us; speedup 1.0000x reference)
//
#include <hip/hip_runtime.h>

// Fused SNN, single main kernel, MFMA pipeline, no contended atomics.
// MI355X (gfx950).
//
// snn_fused: per wave = TWO 16-row tiles. Per tile: GEMM1 (conv as banded
// Toeplitz matmul, transposed so C-layout col = batch row) in nt-pairs ->
// threshold -> packed spike B-fragments (+count) -> GEMM2 -> cur1^T kept in
// f32 REGISTERS (no global round trip). Then 25-step LIF over both tiles
// (2 independent streams for ILP), W2 as 8-reg uniform A-fragment,
// 2 MFMAs/step/tile, coalesced stores. Spike count: per-block partial via
// plain store; finalize_count sums partials (no atomics anywhere).
//
// Contraction-slot bijection (GEMM2/GEMM3 B-side = previous C-layout):
//     k_slot(lk, jj, kt) = 4*lk + (jj&3) + 16*(2*kt + (jj>>2))
// A-side operands are pre-permuted to match by prep_frags.

typedef float    f32x4 __attribute__((ext_vector_type(4)));
typedef short    s16x8 __attribute__((ext_vector_type(8)));

constexpr int L = 187;
constexpr int H = 50;
constexpr int NST = 25;
constexpr float BETA = 0.95f;
constexpr float YTH  = 0.25f;      // y*2 > 0.5  <=>  y > 0.25

constexpr int TTA_SH = 12 * 6 * 64 * 8;   // GEMM1 A fragments
constexpr int W1A_SH = 4 * 6 * 64 * 8;    // GEMM2 A fragments
constexpr int W2A_SH = 2 * 64 * 8;        // GEMM3 A fragments
constexpr int NPART  = 4096;              // per-block count partials (max)

__device__ inline unsigned short f2bf(float f) {
    union { float f; unsigned u; } v; v.f = f;
    return (unsigned short)((v.u + 0x7FFFu + ((v.u >> 16) & 1u)) >> 16);  // RNE
}

// one thread per output short; total = TTA_SH + W1A_SH + W2A_SH = 50176
__global__ void __launch_bounds__(256) prep_frags(
    const float* __restrict__ filt, const float* __restrict__ W1,
    const float* __restrict__ W2,
    unsigned short* __restrict__ TtA, unsigned short* __restrict__ W1A,
    unsigned short* __restrict__ W2A)
{
    int i = blockIdx.x * 256 + threadIdx.x;
    if (i < TTA_SH) {
        // A[l][k]: l = 16*nt + lm, k = 32*kt + 8*lk + jj, val = filt[k-l+24]
        int jj = i & 7, lane = (i >> 3) & 63, kt = (i >> 9) % 6, nt = i / (512 * 6);
        int lm = lane & 15, lk = lane >> 4;
        int l = 16 * nt + lm;
        int k = 32 * kt + 8 * lk + jj;
        int d = k - l + 24;
        unsigned short v = 0;
        if (l < L && k < L && d >= 0 && d < 50) v = f2bf(filt[d]);
        TtA[i] = v;
    } else if (i < TTA_SH + W1A_SH) {
        // A[h][l] permuted: h = 16*mt + lm, l = k_slot(lk,jj,kt)
        int i2 = i - TTA_SH;
        int jj = i2 & 7, lane = (i2 >> 3) & 63, kt = (i2 >> 9) % 6, mt = i2 / (512 * 6);
        int lm = lane & 15, lk = lane >> 4;
        int h = 16 * mt + lm;
        int l = 4 * lk + (jj & 3) + 16 * (2 * kt + (jj >> 2));
        unsigned short v = 0;
        if (h < H && l < L) v = f2bf(W1[h * L + l]);
        W1A[i2] = v;
    } else {
        // A[c][h] permuted: c = lm, h = k_slot(lk,jj,kt)
        int i3 = i - TTA_SH - W1A_SH;
        int jj = i3 & 7, lane = (i3 >> 3) & 63, kt = i3 >> 9;   // kt = 0,1
        int lm = lane & 15, lk = lane >> 4;
        int h = 4 * lk + (jj & 3) + 16 * (2 * kt + (jj >> 2));
        unsigned short v = 0;
        if (lm < 5 && h < H) v = f2bf(W2[lm * H + h]);
        W2A[i3] = v;
    }
}

// ======================= fused main kernel ===================================
__global__ void __launch_bounds__(256, 4) snn_fused(
    const float* __restrict__ x,
    const unsigned short* __restrict__ TtA,
    const unsigned short* __restrict__ W1A,
    const unsigned short* __restrict__ W2A,
    float* __restrict__ out, unsigned int* __restrict__ part, int B)
{
    __shared__ unsigned int csh[4];

    const int tid = threadIdx.x;
    const int wid = tid >> 6, lane = tid & 63;
    const int lm = lane & 15, lk = lane >> 4;
    const int t0 = (blockIdx.x * 4 + wid) * 2;   // two adjacent tiles

    f32x4 cu[2][4];
    int scnt = 0;

    // -------- GEMM phase, one tile at a time (xB/spkB freed between) --------
    #pragma unroll
    for (int T = 0; T < 2; ++T) {
        const int row = (t0 + T) * 16 + lm;

        // xB: B-fragments of GEMM1 (canonical slots)
        s16x8 xB[6];
        {
            const float* __restrict__ xr = x + (size_t)row * L;
            #pragma unroll
            for (int kt = 0; kt < 6; ++kt) {
                const int k0 = 32 * kt + 8 * lk;
                s16x8 v;
                if (k0 + 8 <= L) {
                    float t[8];
                    __builtin_memcpy(t, xr + k0, 32);
                    #pragma unroll
                    for (int jj = 0; jj < 8; ++jj) v[jj] = (short)f2bf(t[jj]);
                } else {
                    #pragma unroll
                    for (int jj = 0; jj < 8; ++jj) {
                        int k = k0 + jj;
                        v[jj] = (short)f2bf((k < L) ? xr[k] : 0.f);
                    }
                }
                xB[kt] = v;
            }
        }

        // GEMM1 by nt-pairs: only 2 accumulators live at a time
        s16x8 spkB[6];
        {
            constexpr int lo[6] = {0, 0, 1, 2, 3, 4};
            constexpr int hi[6] = {1, 2, 3, 4, 5, 5};
            #pragma unroll
            for (int p = 0; p < 6; ++p) {
                f32x4 y0 = (f32x4){0, 0, 0, 0}, y1 = (f32x4){0, 0, 0, 0};
                #pragma unroll
                for (int kt = 0; kt < 6; ++kt) {
                    if (kt >= lo[p] && kt <= hi[p]) {
                        s16x8 a0 = *(const s16x8*)(TtA + ((size_t)((2 * p    ) * 6 + kt) * 64 + lane) * 8);
                        s16x8 a1 = *(const s16x8*)(TtA + ((size_t)((2 * p + 1) * 6 + kt) * 64 + lane) * 8);
                        y0 = __builtin_amdgcn_mfma_f32_16x16x32_bf16(a0, xB[kt], y0, 0, 0, 0);
                        y1 = __builtin_amdgcn_mfma_f32_16x16x32_bf16(a1, xB[kt], y1, 0, 0, 0);
                    }
                }
                union { unsigned w[4]; s16x8 v; } pk;
                #pragma unroll
                for (int w = 0; w < 4; ++w) {
                    float va = (w < 2) ? y0[2 * w]     : y1[2 * (w - 2)];
                    float vb = (w < 2) ? y0[2 * w + 1] : y1[2 * (w - 2) + 1];
                    bool s0 = va > YTH, s1 = vb > YTH;
                    scnt += (int)s0 + (int)s1;
                    pk.w[w] = (s0 ? 0x3F80u : 0u) | (s1 ? 0x3F800000u : 0u);
                }
                spkB[p] = pk.v;
            }
        }

        // GEMM2: cur1^T[h][row] -> f32 registers (no global round trip)
        #pragma unroll
        for (int mt = 0; mt < 4; ++mt) cu[T][mt] = (f32x4){0, 0, 0, 0};
        #pragma unroll
        for (int mt = 0; mt < 4; ++mt)
            #pragma unroll
            for (int kt = 0; kt < 6; ++kt) {
                s16x8 a = *(const s16x8*)(W1A + ((size_t)(mt * 6 + kt) * 64 + lane) * 8);
                cu[T][mt] = __builtin_amdgcn_mfma_f32_16x16x32_bf16(a, spkB[kt], cu[T][mt], 0, 0, 0);
            }
    }

    // per-block partial count: wave reduce -> LDS -> one plain store
    #pragma unroll
    for (int off = 32; off; off >>= 1) scnt += __shfl_down(scnt, off);
    if (lane == 0) csh[wid] = (unsigned)scnt;
    __syncthreads();
    if (tid == 0) part[blockIdx.x] = csh[0] + csh[1] + csh[2] + csh[3];

    // -------- LIF phase: 25 steps, 2 independent streams ---------------------
    s16x8 w2a[2];
    #pragma unroll
    for (int kt = 0; kt < 2; ++kt)
        w2a[kt] = *(const s16x8*)(W2A + ((size_t)kt * 64 + lane) * 8);

    f32x4 m1[2][4], m2[2];
    #pragma unroll
    for (int T = 0; T < 2; ++T) {
        #pragma unroll
        for (int mt = 0; mt < 4; ++mt) m1[T][mt] = (f32x4){0, 0, 0, 0};
        m2[T] = (f32x4){0, 0, 0, 0};
    }

    float* __restrict__ po[2];
    #pragma unroll
    for (int T = 0; T < 2; ++T) po[T] = out + (size_t)((t0 + T) * 16 + lm) * 5;
    const size_t step = (size_t)B * 5;

    #pragma unroll 1
    for (int t = 0; t < NST; ++t) {
        const size_t toff = (size_t)t * step;
        #pragma unroll
        for (int T = 0; T < 2; ++T) {
            // m1 update + spk1 pack into permuted B-fragments
            s16x8 s1b[2];
            #pragma unroll
            for (int kt = 0; kt < 2; ++kt) {
                union { unsigned w[4]; s16x8 v; } pk;
                #pragma unroll
                for (int w = 0; w < 4; ++w) {
                    const int jj0 = 2 * w, jj1 = 2 * w + 1;
                    const int mt0 = 2 * kt + (jj0 >> 2), j0 = jj0 & 3;
                    const int mt1 = 2 * kt + (jj1 >> 2), j1 = jj1 & 3;
                    float ma = fmaf(BETA, m1[T][mt0][j0], cu[T][mt0][j0]);
                    float mb = fmaf(BETA, m1[T][mt1][j1], cu[T][mt1][j1]);
                    bool sa = ma > 1.f, sb = mb > 1.f;
                    m1[T][mt0][j0] = sa ? ma - 1.f : ma;
                    m1[T][mt1][j1] = sb ? mb - 1.f : mb;
                    pk.w[w] = (sa ? 0x3F80u : 0u) | (sb ? 0x3F800000u : 0u);
                }
                s1b[kt] = pk.v;
            }
            // cur2^T via 2 MFMAs (accumulator-chained)
            f32x4 c2 = (f32x4){0, 0, 0, 0};
            c2 = __builtin_amdgcn_mfma_f32_16x16x32_bf16(w2a[0], s1b[0], c2, 0, 0, 0);
            c2 = __builtin_amdgcn_mfma_f32_16x16x32_bf16(w2a[1], s1b[1], c2, 0, 0, 0);
            // m2 update + store spikes (lane holds c = 4*lk + j)
            f32x4 sv;
            #pragma unroll
            for (int j = 0; j < 4; ++j) {
                float m = fmaf(BETA, m2[T][j], c2[j]);
                bool s = m > 1.f;
                m2[T][j] = s ? m - 1.f : m;
                sv[j] = s ? 1.f : 0.f;
            }
            float* __restrict__ pt = po[T] + toff;
            if (lk == 0) {
                __builtin_memcpy(pt, &sv, 16);        // c = 0..3
            } else if (lk == 1) {
                pt[4] = sv[0];                        // c = 4
            }
        }
    }
}

// sum per-block partials -> out[off] = total * 25   (single block, no atomics)
__global__ void __launch_bounds__(256) finalize_count(
    const unsigned int* __restrict__ part, int n,
    float* __restrict__ out, size_t off)
{
    __shared__ unsigned int sh[4];
    unsigned int s = 0;
    for (int i = threadIdx.x; i < n; i += 256) s += part[i];
    #pragma unroll
    for (int o = 32; o; o >>= 1) s += __shfl_down(s, o);
    if ((threadIdx.x & 63) == 0) sh[threadIdx.x >> 6] = s;
    __syncthreads();
    if (threadIdx.x == 0) {
        unsigned int t = sh[0] + sh[1] + sh[2] + sh[3];
        out[off] = (float)((double)t * 25.0);
    }
}

// ============ fallback: scalar path (only if ws too small) ===================
__global__ void __launch_bounds__(256) snn_fallback(
    const float* __restrict__ x, const float* __restrict__ filt,
    const float* __restrict__ W1, const float* __restrict__ W2,
    float* __restrict__ out, unsigned int* __restrict__ part, int B)
{
    __shared__ unsigned int csh[4];
    const int row = blockIdx.x * 256 + threadIdx.x;
    const bool valid = row < B;
    const int rr = valid ? row : (B - 1);
    const float* __restrict__ xr = x + (size_t)rr * L;
    float w[64], cur1[H];
    #pragma unroll
    for (int h = 0; h < H; ++h) cur1[h] = 0.f;
    int cntv = 0;
    #pragma unroll
    for (int i = 0; i < 64; ++i) w[i] = (i >= 24) ? xr[i - 24] : 0.f;
    #pragma unroll 1
    for (int s = 0; s < 12; ++s) {
        const int l0 = s * 15;
        #pragma unroll
        for (int j = 0; j < 15; ++j) {
            const int l = l0 + j;
            float yv = 0.f;
            #pragma unroll
            for (int k = 0; k < 50; ++k) yv = fmaf(w[j + k], filt[k], yv);
            const bool sb = yv > YTH;
            cntv += sb;
            const float sp = sb ? 1.f : 0.f;
            #pragma unroll
            for (int h = 0; h < H; ++h) cur1[h] = fmaf(sp, W1[h * L + l], cur1[h]);
        }
        #pragma unroll
        for (int i = 0; i < 49; ++i) w[i] = w[i + 15];
        #pragma unroll
        for (int d = 0; d < 15; ++d) {
            const int g = l0 + 40 + d;
            w[49 + d] = (g < L) ? xr[g] : 0.f;
        }
    }
    #pragma unroll
    for (int j = 0; j < 7; ++j) {
        const int l = 180 + j;
        float yv = 0.f;
        #pragma unroll
        for (int k = 0; k < 50; ++k) yv = fmaf(w[j + k], filt[k], yv);
        const bool sb = yv > YTH;
        cntv += sb;
        const float sp = sb ? 1.f : 0.f;
        #pragma unroll
        for (int h = 0; h < H; ++h) cur1[h] = fmaf(sp, W1[h * L + l], cur1[h]);
    }
    int wc = valid ? cntv : 0;
    #pragma unroll
    for (int off = 32; off; off >>= 1) wc += __shfl_down(wc, off);
    if ((threadIdx.x & 63) == 0) csh[threadIdx.x >> 6] = (unsigned)wc;
    __syncthreads();
    if (threadIdx.x == 0) part[blockIdx.x] = csh[0] + csh[1] + csh[2] + csh[3];
    float m1[H], m2[5];
    #pragma unroll
    for (int h = 0; h < H; ++h) m1[h] = 0.f;
    #pragma unroll
    for (int c = 0; c < 5; ++c) m2[c] = 0.f;
    #pragma unroll 1
    for (int t = 0; t < NST; ++t) {
        float c2[5] = {0, 0, 0, 0, 0};
        #pragma unroll
        for (int h = 0; h < H; ++h) {
            float m = fmaf(BETA, m1[h], cur1[h]);
            const float sp = (m > 1.f) ? 1.f : 0.f;
            m1[h] = m - sp;
            #pragma unroll
            for (int c = 0; c < 5; ++c) c2[c] = fmaf(sp, W2[c * H + h], c2[c]);
        }
        float* __restrict__ ot = out + ((size_t)t * B + rr) * 5;
        #pragma unroll
        for (int c = 0; c < 5; ++c) {
            float m = fmaf(BETA, m2[c], c2[c]);
            const float s2 = (m > 1.f) ? 1.f : 0.f;
            m2[c] = m - s2;
            if (valid) ot[c] = s2;
        }
    }
}

extern "C" void kernel_launch(void* const* d_in, const int* in_sizes, int n_in,
                              void* d_out, int out_size, void* d_ws, size_t ws_size,
                              hipStream_t stream)
{
    const float* x    = (const float*)d_in[0];
    const float* filt = (const float*)d_in[1];
    const float* W1   = (const float*)d_in[2];
    const float* W2   = (const float*)d_in[3];
    float* out        = (float*)d_out;
    const int B       = in_sizes[0] / L;          // 131072

    unsigned int* part  = (unsigned int*)d_ws;    // NPART entries
    unsigned short* TtA = (unsigned short*)((char*)d_ws + NPART * 4);
    unsigned short* W1A = TtA + TTA_SH;
    unsigned short* W2A = W1A + W1A_SH;
    const size_t need = (size_t)NPART * 4 + (size_t)(TTA_SH + W1A_SH + W2A_SH) * 2;

    if (ws_size >= need && (B % 128) == 0) {
        const int total = TTA_SH + W1A_SH + W2A_SH;   // 50176
        prep_frags<<<(total + 255) / 256, 256, 0, stream>>>(filt, W1, W2, TtA, W1A, W2A);
        snn_fused<<<B / 128, 256, 0, stream>>>(x, TtA, W1A, W2A, out, part, B);
        finalize_count<<<1, 256, 0, stream>>>(part, B / 128, out, (size_t)NST * B * 5);
    } else {
        snn_fallback<<<(B + 255) / 256, 256, 0, stream>>>(x, filt, W1, W2, out, part, B);
        finalize_count<<<1, 256, 0, stream>>>(part, (B + 255) / 256, out, (size_t)NST * B * 5);
    }
}

// Round 8
// 63.647 us; speedup vs baseline: 1.3683x; 1.3683x over previous
//
#include <hip/hip_runtime.h>

// Fused SNN, single main kernel, 1 tile/wave (spill-free R4 structure),
// block-partial spike count (no contended atomics). MI355X (gfx950).
//
// Per wave = ONE 16-row tile: GEMM1 (conv as banded Toeplitz matmul,
// transposed so C-layout col = batch row) in nt-pairs -> threshold ->
// packed spike B-fragments (+count) -> GEMM2 -> cur1^T in f32 registers ->
// 25-step LIF with W2 as 8-reg uniform A-fragment, 2 MFMAs/step,
// coalesced stores. Spike count: wave reduce -> LDS -> per-block partial
// plain store; finalize_count sums partials.
//
// Contraction-slot bijection (GEMM2/GEMM3 B-side = previous C-layout):
//     k_slot(lk, jj, kt) = 4*lk + (jj&3) + 16*(2*kt + (jj>>2))
// A-side operands are pre-permuted to match by prep_frags.

typedef float    f32x4 __attribute__((ext_vector_type(4)));
typedef short    s16x8 __attribute__((ext_vector_type(8)));

constexpr int L = 187;
constexpr int H = 50;
constexpr int NST = 25;
constexpr float BETA = 0.95f;
constexpr float YTH  = 0.25f;      // y*2 > 0.5  <=>  y > 0.25

constexpr int TTA_SH = 12 * 6 * 64 * 8;   // GEMM1 A fragments
constexpr int W1A_SH = 4 * 6 * 64 * 8;    // GEMM2 A fragments
constexpr int W2A_SH = 2 * 64 * 8;        // GEMM3 A fragments
constexpr int NPART  = 4096;              // per-block count partials (max)

__device__ inline unsigned short f2bf(float f) {
    union { float f; unsigned u; } v; v.f = f;
    return (unsigned short)((v.u + 0x7FFFu + ((v.u >> 16) & 1u)) >> 16);  // RNE
}

// one thread per output short; total = TTA_SH + W1A_SH + W2A_SH = 50176
__global__ void __launch_bounds__(256) prep_frags(
    const float* __restrict__ filt, const float* __restrict__ W1,
    const float* __restrict__ W2,
    unsigned short* __restrict__ TtA, unsigned short* __restrict__ W1A,
    unsigned short* __restrict__ W2A)
{
    int i = blockIdx.x * 256 + threadIdx.x;
    if (i < TTA_SH) {
        // A[l][k]: l = 16*nt + lm, k = 32*kt + 8*lk + jj, val = filt[k-l+24]
        int jj = i & 7, lane = (i >> 3) & 63, kt = (i >> 9) % 6, nt = i / (512 * 6);
        int lm = lane & 15, lk = lane >> 4;
        int l = 16 * nt + lm;
        int k = 32 * kt + 8 * lk + jj;
        int d = k - l + 24;
        unsigned short v = 0;
        if (l < L && k < L && d >= 0 && d < 50) v = f2bf(filt[d]);
        TtA[i] = v;
    } else if (i < TTA_SH + W1A_SH) {
        // A[h][l] permuted: h = 16*mt + lm, l = k_slot(lk,jj,kt)
        int i2 = i - TTA_SH;
        int jj = i2 & 7, lane = (i2 >> 3) & 63, kt = (i2 >> 9) % 6, mt = i2 / (512 * 6);
        int lm = lane & 15, lk = lane >> 4;
        int h = 16 * mt + lm;
        int l = 4 * lk + (jj & 3) + 16 * (2 * kt + (jj >> 2));
        unsigned short v = 0;
        if (h < H && l < L) v = f2bf(W1[h * L + l]);
        W1A[i2] = v;
    } else {
        // A[c][h] permuted: c = lm, h = k_slot(lk,jj,kt)
        int i3 = i - TTA_SH - W1A_SH;
        int jj = i3 & 7, lane = (i3 >> 3) & 63, kt = i3 >> 9;   // kt = 0,1
        int lm = lane & 15, lk = lane >> 4;
        int h = 4 * lk + (jj & 3) + 16 * (2 * kt + (jj >> 2));
        unsigned short v = 0;
        if (lm < 5 && h < H) v = f2bf(W2[lm * H + h]);
        W2A[i3] = v;
    }
}

// ======================= fused main kernel (1 tile / wave) ===================
__global__ void __launch_bounds__(256, 4) snn_fused(
    const float* __restrict__ x,
    const unsigned short* __restrict__ TtA,
    const unsigned short* __restrict__ W1A,
    const unsigned short* __restrict__ W2A,
    float* __restrict__ out, unsigned int* __restrict__ part, int B)
{
    __shared__ unsigned int csh[4];

    const int tid = threadIdx.x;
    const int wid = tid >> 6, lane = tid & 63;
    const int lm = lane & 15, lk = lane >> 4;
    const int row = blockIdx.x * 64 + wid * 16 + lm;

    // xB: B-fragments of GEMM1 (canonical slots)
    s16x8 xB[6];
    {
        const float* __restrict__ xr = x + (size_t)row * L;
        #pragma unroll
        for (int kt = 0; kt < 6; ++kt) {
            const int k0 = 32 * kt + 8 * lk;
            s16x8 v;
            if (k0 + 8 <= L) {
                float t[8];
                __builtin_memcpy(t, xr + k0, 32);
                #pragma unroll
                for (int jj = 0; jj < 8; ++jj) v[jj] = (short)f2bf(t[jj]);
            } else {
                #pragma unroll
                for (int jj = 0; jj < 8; ++jj) {
                    int k = k0 + jj;
                    v[jj] = (short)f2bf((k < L) ? xr[k] : 0.f);
                }
            }
            xB[kt] = v;
        }
    }

    // GEMM1 by nt-pairs: only 2 accumulators live at a time
    int scnt = 0;
    s16x8 spkB[6];
    {
        constexpr int lo[6] = {0, 0, 1, 2, 3, 4};
        constexpr int hi[6] = {1, 2, 3, 4, 5, 5};
        #pragma unroll
        for (int p = 0; p < 6; ++p) {
            f32x4 y0 = (f32x4){0, 0, 0, 0}, y1 = (f32x4){0, 0, 0, 0};
            #pragma unroll
            for (int kt = 0; kt < 6; ++kt) {
                if (kt >= lo[p] && kt <= hi[p]) {
                    s16x8 a0 = *(const s16x8*)(TtA + ((size_t)((2 * p    ) * 6 + kt) * 64 + lane) * 8);
                    s16x8 a1 = *(const s16x8*)(TtA + ((size_t)((2 * p + 1) * 6 + kt) * 64 + lane) * 8);
                    y0 = __builtin_amdgcn_mfma_f32_16x16x32_bf16(a0, xB[kt], y0, 0, 0, 0);
                    y1 = __builtin_amdgcn_mfma_f32_16x16x32_bf16(a1, xB[kt], y1, 0, 0, 0);
                }
            }
            // pack pair -> spkB[p]
            union { unsigned w[4]; s16x8 v; } pk;
            #pragma unroll
            for (int w = 0; w < 4; ++w) {
                float va = (w < 2) ? y0[2 * w]     : y1[2 * (w - 2)];
                float vb = (w < 2) ? y0[2 * w + 1] : y1[2 * (w - 2) + 1];
                bool s0 = va > YTH, s1 = vb > YTH;
                scnt += (int)s0 + (int)s1;
                pk.w[w] = (s0 ? 0x3F80u : 0u) | (s1 ? 0x3F800000u : 0u);
            }
            spkB[p] = pk.v;
        }
    }
    // per-block partial count: wave reduce -> LDS -> one plain store
    #pragma unroll
    for (int off = 32; off; off >>= 1) scnt += __shfl_down(scnt, off);
    if (lane == 0) csh[wid] = (unsigned)scnt;
    __syncthreads();
    if (tid == 0) part[blockIdx.x] = csh[0] + csh[1] + csh[2] + csh[3];

    // GEMM2: cur1^T[h][row] -> f32 registers
    f32x4 cu[4];
    #pragma unroll
    for (int mt = 0; mt < 4; ++mt) cu[mt] = (f32x4){0, 0, 0, 0};
    #pragma unroll
    for (int mt = 0; mt < 4; ++mt)
        #pragma unroll
        for (int kt = 0; kt < 6; ++kt) {
            s16x8 a = *(const s16x8*)(W1A + ((size_t)(mt * 6 + kt) * 64 + lane) * 8);
            cu[mt] = __builtin_amdgcn_mfma_f32_16x16x32_bf16(a, spkB[kt], cu[mt], 0, 0, 0);
        }

    // W2 A-fragments (8 VGPRs)
    s16x8 w2a[2];
    #pragma unroll
    for (int kt = 0; kt < 2; ++kt)
        w2a[kt] = *(const s16x8*)(W2A + ((size_t)kt * 64 + lane) * 8);

    // -------- LIF: 25 steps, all in registers --------
    f32x4 m1[4];
    #pragma unroll
    for (int mt = 0; mt < 4; ++mt) m1[mt] = (f32x4){0, 0, 0, 0};
    f32x4 m2 = (f32x4){0, 0, 0, 0};

    float* __restrict__ po = out + (size_t)row * 5;
    const size_t step = (size_t)B * 5;

    #pragma unroll 1
    for (int t = 0; t < NST; ++t) {
        // m1 update + spk1 pack into permuted B-fragments
        s16x8 s1b[2];
        #pragma unroll
        for (int kt = 0; kt < 2; ++kt) {
            union { unsigned w[4]; s16x8 v; } pk;
            #pragma unroll
            for (int w = 0; w < 4; ++w) {
                const int jj0 = 2 * w, jj1 = 2 * w + 1;
                const int mt0 = 2 * kt + (jj0 >> 2), j0 = jj0 & 3;
                const int mt1 = 2 * kt + (jj1 >> 2), j1 = jj1 & 3;
                float ma = fmaf(BETA, m1[mt0][j0], cu[mt0][j0]);
                float mb = fmaf(BETA, m1[mt1][j1], cu[mt1][j1]);
                bool sa = ma > 1.f, sb = mb > 1.f;
                m1[mt0][j0] = sa ? ma - 1.f : ma;
                m1[mt1][j1] = sb ? mb - 1.f : mb;
                pk.w[w] = (sa ? 0x3F80u : 0u) | (sb ? 0x3F800000u : 0u);
            }
            s1b[kt] = pk.v;
        }
        // cur2^T via 2 MFMAs (accumulator-chained)
        f32x4 c2 = (f32x4){0, 0, 0, 0};
        c2 = __builtin_amdgcn_mfma_f32_16x16x32_bf16(w2a[0], s1b[0], c2, 0, 0, 0);
        c2 = __builtin_amdgcn_mfma_f32_16x16x32_bf16(w2a[1], s1b[1], c2, 0, 0, 0);
        // m2 update + store spikes (lane holds c = 4*lk + j)
        f32x4 sv;
        #pragma unroll
        for (int j = 0; j < 4; ++j) {
            float m = fmaf(BETA, m2[j], c2[j]);
            bool s = m > 1.f;
            m2[j] = s ? m - 1.f : m;
            sv[j] = s ? 1.f : 0.f;
        }
        float* __restrict__ pt = po + (size_t)t * step;
        if (lk == 0) {
            __builtin_memcpy(pt, &sv, 16);        // c = 0..3
        } else if (lk == 1) {
            pt[4] = sv[0];                        // c = 4
        }
    }
}

// sum per-block partials -> out[off] = total * 25   (single block, no atomics)
__global__ void __launch_bounds__(256) finalize_count(
    const unsigned int* __restrict__ part, int n,
    float* __restrict__ out, size_t off)
{
    __shared__ unsigned int sh[4];
    unsigned int s = 0;
    for (int i = threadIdx.x; i < n; i += 256) s += part[i];
    #pragma unroll
    for (int o = 32; o; o >>= 1) s += __shfl_down(s, o);
    if ((threadIdx.x & 63) == 0) sh[threadIdx.x >> 6] = s;
    __syncthreads();
    if (threadIdx.x == 0) {
        unsigned int t = sh[0] + sh[1] + sh[2] + sh[3];
        out[off] = (float)((double)t * 25.0);
    }
}

// ============ fallback: scalar path (only if ws too small) ===================
__global__ void __launch_bounds__(256) snn_fallback(
    const float* __restrict__ x, const float* __restrict__ filt,
    const float* __restrict__ W1, const float* __restrict__ W2,
    float* __restrict__ out, unsigned int* __restrict__ part, int B)
{
    __shared__ unsigned int csh[4];
    const int row = blockIdx.x * 256 + threadIdx.x;
    const bool valid = row < B;
    const int rr = valid ? row : (B - 1);
    const float* __restrict__ xr = x + (size_t)rr * L;
    float w[64], cur1[H];
    #pragma unroll
    for (int h = 0; h < H; ++h) cur1[h] = 0.f;
    int cntv = 0;
    #pragma unroll
    for (int i = 0; i < 64; ++i) w[i] = (i >= 24) ? xr[i - 24] : 0.f;
    #pragma unroll 1
    for (int s = 0; s < 12; ++s) {
        const int l0 = s * 15;
        #pragma unroll
        for (int j = 0; j < 15; ++j) {
            const int l = l0 + j;
            float yv = 0.f;
            #pragma unroll
            for (int k = 0; k < 50; ++k) yv = fmaf(w[j + k], filt[k], yv);
            const bool sb = yv > YTH;
            cntv += sb;
            const float sp = sb ? 1.f : 0.f;
            #pragma unroll
            for (int h = 0; h < H; ++h) cur1[h] = fmaf(sp, W1[h * L + l], cur1[h]);
        }
        #pragma unroll
        for (int i = 0; i < 49; ++i) w[i] = w[i + 15];
        #pragma unroll
        for (int d = 0; d < 15; ++d) {
            const int g = l0 + 40 + d;
            w[49 + d] = (g < L) ? xr[g] : 0.f;
        }
    }
    #pragma unroll
    for (int j = 0; j < 7; ++j) {
        const int l = 180 + j;
        float yv = 0.f;
        #pragma unroll
        for (int k = 0; k < 50; ++k) yv = fmaf(w[j + k], filt[k], yv);
        const bool sb = yv > YTH;
        cntv += sb;
        const float sp = sb ? 1.f : 0.f;
        #pragma unroll
        for (int h = 0; h < H; ++h) cur1[h] = fmaf(sp, W1[h * L + l], cur1[h]);
    }
    int wc = valid ? cntv : 0;
    #pragma unroll
    for (int off = 32; off; off >>= 1) wc += __shfl_down(wc, off);
    if ((threadIdx.x & 63) == 0) csh[threadIdx.x >> 6] = (unsigned)wc;
    __syncthreads();
    if (threadIdx.x == 0) part[blockIdx.x] = csh[0] + csh[1] + csh[2] + csh[3];
    float m1[H], m2[5];
    #pragma unroll
    for (int h = 0; h < H; ++h) m1[h] = 0.f;
    #pragma unroll
    for (int c = 0; c < 5; ++c) m2[c] = 0.f;
    #pragma unroll 1
    for (int t = 0; t < NST; ++t) {
        float c2[5] = {0, 0, 0, 0, 0};
        #pragma unroll
        for (int h = 0; h < H; ++h) {
            float m = fmaf(BETA, m1[h], cur1[h]);
            const float sp = (m > 1.f) ? 1.f : 0.f;
            m1[h] = m - sp;
            #pragma unroll
            for (int c = 0; c < 5; ++c) c2[c] = fmaf(sp, W2[c * H + h], c2[c]);
        }
        float* __restrict__ ot = out + ((size_t)t * B + rr) * 5;
        #pragma unroll
        for (int c = 0; c < 5; ++c) {
            float m = fmaf(BETA, m2[c], c2[c]);
            const float s2 = (m > 1.f) ? 1.f : 0.f;
            m2[c] = m - s2;
            if (valid) ot[c] = s2;
        }
    }
}

extern "C" void kernel_launch(void* const* d_in, const int* in_sizes, int n_in,
                              void* d_out, int out_size, void* d_ws, size_t ws_size,
                              hipStream_t stream)
{
    const float* x    = (const float*)d_in[0];
    const float* filt = (const float*)d_in[1];
    const float* W1   = (const float*)d_in[2];
    const float* W2   = (const float*)d_in[3];
    float* out        = (float*)d_out;
    const int B       = in_sizes[0] / L;          // 131072

    unsigned int* part  = (unsigned int*)d_ws;    // NPART entries
    unsigned short* TtA = (unsigned short*)((char*)d_ws + NPART * 4);
    unsigned short* W1A = TtA + TTA_SH;
    unsigned short* W2A = W1A + W1A_SH;
    const size_t need = (size_t)NPART * 4 + (size_t)(TTA_SH + W1A_SH + W2A_SH) * 2;

    if (ws_size >= need && (B % 64) == 0 && B / 64 <= NPART) {
        const int total = TTA_SH + W1A_SH + W2A_SH;   // 50176
        prep_frags<<<(total + 255) / 256, 256, 0, stream>>>(filt, W1, W2, TtA, W1A, W2A);
        snn_fused<<<B / 64, 256, 0, stream>>>(x, TtA, W1A, W2A, out, part, B);
        finalize_count<<<1, 256, 0, stream>>>(part, B / 64, out, (size_t)NST * B * 5);
    } else {
        snn_fallback<<<(B + 255) / 256, 256, 0, stream>>>(x, filt, W1, W2, out, part, B);
        finalize_count<<<1, 256, 0, stream>>>(part, (B + 255) / 256, out, (size_t)NST * B * 5);
    }
}